// Round 5
// baseline (779.809 us; speedup 1.0000x reference)
//
#include <hip/hip_runtime.h>
#include <cstddef>
#include <cstdint>

#define BATCH 16
#define CIN 64
#define COUT 64
#define HH 256
#define WW 256
#define HID 17
#define KNUM 4

typedef __attribute__((ext_vector_type(4))) float f32x4;
typedef __attribute__((ext_vector_type(8))) short s16x8;

static __device__ __forceinline__ unsigned short f2bf(float f) {
    unsigned u = __builtin_bit_cast(unsigned, f);
    u += 0x7FFFu + ((u >> 16) & 1u);   // RNE
    return (unsigned short)(u >> 16);
}

// ================= NEW PATH =================
// xpad layout: [b][r][cpad 0..257][ch 0..63] bf16, cpad = real col + 1, cols 0/257 zero.
#define XROWSTR 16512              // 258*64 shorts per row
#define XBSTR   4227072            // 256*XROWSTR shorts per batch

// ---- kernel A: fused transpose (fp32 NCHW -> bf16 padded NHWC) + global avg pool ----
__global__ __launch_bounds__(256) void tpose_pool_kernel(const float* __restrict__ x,
                                                         short* __restrict__ xpad,
                                                         float* __restrict__ pooled) {
    const int b = blockIdx.z;
    const int r = blockIdx.y;
    const int half = blockIdx.x;         // 0/1: which 128-px half of the row
    const int tid = threadIdx.x;
    const int wave = tid >> 6;
    const int lane = tid & 63;
    const int w4 = lane >> 3;            // 0..7
    const int g  = lane & 7;             // channel-group 0..7 (8 ch each)
    const int px0 = half * 128 + wave * 32 + w4 * 4;

    const float* xb = x + (size_t)b * (CIN * HH * WW) + (size_t)r * WW + px0;
    float4 v[8];
    #pragma unroll
    for (int gi = 0; gi < 8; ++gi)
        v[gi] = *(const float4*)(xb + (size_t)(g * 8 + gi) * (HH * WW));

    // write 4 pixels x 8 channels (16B each), coalesced in 128B chunks per 8 lanes
    short* dst0 = xpad + ((size_t)b * 256 + r) * XROWSTR + (size_t)(1 + px0) * 64 + g * 8;
    #pragma unroll
    for (int j = 0; j < 4; ++j) {
        float f[8];
        f[0]=v[0][j]; f[1]=v[1][j]; f[2]=v[2][j]; f[3]=v[3][j];
        f[4]=v[4][j]; f[5]=v[5][j]; f[6]=v[6][j]; f[7]=v[7][j];
        uint4 pk;
        pk.x = (unsigned)f2bf(f[0]) | ((unsigned)f2bf(f[1]) << 16);
        pk.y = (unsigned)f2bf(f[2]) | ((unsigned)f2bf(f[3]) << 16);
        pk.z = (unsigned)f2bf(f[4]) | ((unsigned)f2bf(f[5]) << 16);
        pk.w = (unsigned)f2bf(f[6]) | ((unsigned)f2bf(f[7]) << 16);
        *(uint4*)(dst0 + (size_t)j * 64) = pk;
    }

    // pooling partials: thread has 8 channels x 4 px
    float ps[8];
    #pragma unroll
    for (int gi = 0; gi < 8; ++gi) ps[gi] = v[gi].x + v[gi].y + v[gi].z + v[gi].w;
    #pragma unroll
    for (int off = 8; off < 64; off <<= 1)
        #pragma unroll
        for (int gi = 0; gi < 8; ++gi) ps[gi] += __shfl_xor(ps[gi], off, 64);

    __shared__ float pl[4][64];
    if (w4 == 0) {
        #pragma unroll
        for (int gi = 0; gi < 8; ++gi) pl[wave][g * 8 + gi] = ps[gi];
    }
    __syncthreads();
    if (tid < 64)
        atomicAdd(&pooled[b * 64 + tid], pl[0][tid] + pl[1][tid] + pl[2][tid] + pl[3][tid]);

    // zero pad columns (cpad 0 for half==0, cpad 257 for half==1)
    if (tid < 8) {
        short* pz = xpad + ((size_t)b * 256 + r) * XROWSTR + (size_t)(half ? 257 : 0) * 64 + tid * 8;
        *(uint4*)pz = (uint4){0u, 0u, 0u, 0u};
    }
}

// ---- kernel B: fused attention + agg bias + agg weights (bf16 packed) ----
// grid (9, BATCH); block (b,t) writes agg_wb[b][t][o][i/2]
__global__ __launch_bounds__(256) void att_aggw_kernel(const float* __restrict__ pooled,
                                                       const float* __restrict__ fc1_w,
                                                       const float* __restrict__ fc2_w,
                                                       const float* __restrict__ fc2_b,
                                                       const float* __restrict__ bias_k,
                                                       const float* __restrict__ weight,
                                                       float* __restrict__ agg_b,
                                                       unsigned* __restrict__ agg_wb) {
    const int t = blockIdx.x;
    const int b = blockIdx.y;
    const int tid = threadIdx.x;
    __shared__ float h_l[HID];
    __shared__ float att_l[KNUM];

    if (tid < HID) {
        float s = 0.f;
        for (int c = 0; c < CIN; ++c) s += pooled[b * CIN + c] * fc1_w[tid * CIN + c];
        s *= (1.0f / (HH * WW));   // pooled holds sums; fold the mean here
        h_l[tid] = (s >= 0.f) ? s : 0.2f * s;
    }
    __syncthreads();
    if (tid == 0) {
        float lg[KNUM];
        float m = -1e30f;
        for (int k = 0; k < KNUM; ++k) {
            float s = fc2_b[k];
            for (int j = 0; j < HID; ++j) s += h_l[j] * fc2_w[k * HID + j];
            lg[k] = s * (1.0f / 34.0f);
            m = fmaxf(m, lg[k]);
        }
        float sum = 0.f;
        for (int k = 0; k < KNUM; ++k) { lg[k] = expf(lg[k] - m); sum += lg[k]; }
        float inv = 1.0f / sum;
        for (int k = 0; k < KNUM; ++k) att_l[k] = lg[k] * inv;
    }
    __syncthreads();
    const float a0 = att_l[0], a1 = att_l[1], a2 = att_l[2], a3 = att_l[3];

    if (t == 0 && tid < COUT) {
        float s = a0 * bias_k[tid] + a1 * bias_k[COUT + tid] +
                  a2 * bias_k[2 * COUT + tid] + a3 * bias_k[3 * COUT + tid];
        agg_b[b * COUT + tid] = s;
    }

    const size_t kstr = (size_t)COUT * CIN * 9;  // 36864
    unsigned* dst = agg_wb + (size_t)b * (9 * COUT * 32) + (size_t)t * (COUT * 32);
    #pragma unroll
    for (int e8 = 0; e8 < 8; ++e8) {
        int e = tid * 8 + e8;
        int o = e >> 5, ip = e & 31, i = 2 * ip;
        const float* w0 = weight + ((size_t)(o * CIN + i) * 9 + t);
        float s0 = a0 * w0[0] + a1 * w0[kstr] + a2 * w0[2 * kstr] + a3 * w0[3 * kstr];
        const float* w1 = w0 + 9;
        float s1 = a0 * w1[0] + a1 * w1[kstr] + a2 * w1[2 * kstr] + a3 * w1[3 * kstr];
        dst[e] = (unsigned)f2bf(s0) | ((unsigned)f2bf(s1) << 16);
    }
}

// ---- kernel C: NHWC implicit-GEMM conv, no LDS, no barriers ----
// block = 4 waves = one output row (b,r); wave wv covers cols wv*64..+63, all 64 o.
__global__ __launch_bounds__(256) void conv_nhwc_kernel(const short* __restrict__ xpad,
                                                        const unsigned* __restrict__ agg_wb,
                                                        const float* __restrict__ agg_b,
                                                        float* __restrict__ out) {
    // XCD-chunked swizzle: 4096 blocks -> 8 chunks of 512 (same-b rows stay on one XCD)
    const int swz = (blockIdx.x & 7) * 512 + (blockIdx.x >> 3);
    const int b = swz >> 8;
    const int r = swz & 255;
    const int lane = threadIdx.x & 63;
    const int wv = threadIdx.x >> 6;
    const int l15 = lane & 15;
    const int q = lane >> 4;
    const int w0 = wv * 64;

    const unsigned* wb = agg_wb + (size_t)b * (9 * COUT * 32);

    f32x4 acc[4][4];
    #pragma unroll
    for (int mt = 0; mt < 4; ++mt)
        #pragma unroll
        for (int nt = 0; nt < 4; ++nt) acc[mt][nt] = (f32x4){0.f, 0.f, 0.f, 0.f};

    for (int t = 0; t < 9; ++t) {
        const int dh = t / 3;
        const int dw = t - dh * 3;
        const int rp = r + dh - 1;
        if ((unsigned)rp >= HH) continue;   // uniform over block: zero-pad rows
        const short* xrow = xpad + ((size_t)b * 256 + rp) * XROWSTR;
        #pragma unroll
        for (int ic = 0; ic < 2; ++ic) {
            s16x8 af[4];
            #pragma unroll
            for (int mt = 0; mt < 4; ++mt)
                af[mt] = *(const s16x8*)(wb + ((size_t)(t * COUT + mt * 16 + l15) * 32 + ic * 16 + q * 4));
            #pragma unroll
            for (int nt = 0; nt < 4; ++nt) {
                const short* bp = xrow + (size_t)(w0 + nt * 16 + l15 + dw) * 64 + ic * 32 + q * 8;
                s16x8 bf = *(const s16x8*)bp;
                #pragma unroll
                for (int mt = 0; mt < 4; ++mt)
                    acc[mt][nt] = __builtin_amdgcn_mfma_f32_16x16x32_bf16(af[mt], bf, acc[mt][nt], 0, 0, 0);
            }
        }
    }

    const float* bb = agg_b + b * COUT;
    float* op = out + (size_t)b * (COUT * HH * WW) + (size_t)r * WW;
    #pragma unroll
    for (int mt = 0; mt < 4; ++mt) {
        #pragma unroll
        for (int rg = 0; rg < 4; ++rg) {
            int o = mt * 16 + q * 4 + rg;
            float bv = bb[o];
            #pragma unroll
            for (int nt = 0; nt < 4; ++nt)
                op[(size_t)o * (HH * WW) + w0 + nt * 16 + l15] = acc[mt][nt][rg] + bv;
        }
    }
}

// ================= FALLBACK PATH (round-4, passed) =================
#define TH 8
#define TW 32
#define XROWS (TH + 2)
#define XCOLS (TW + 2)
#define NPIX (XROWS * XCOLS)
#define XSTR 72
#define XSTR32 36

__global__ __launch_bounds__(256) void pool_kernel(const float* __restrict__ x,
                                                   float* __restrict__ pooled) {
    int bc = blockIdx.x;
    const float4* p = (const float4*)(x + (size_t)bc * (HH * WW));
    float s = 0.f;
    for (int idx = threadIdx.x; idx < HH * WW / 4; idx += 256) {
        float4 v = p[idx];
        s += v.x + v.y + v.z + v.w;
    }
    #pragma unroll
    for (int off = 32; off > 0; off >>= 1) s += __shfl_down(s, off, 64);
    __shared__ float wsum[4];
    int lane = threadIdx.x & 63, wvi = threadIdx.x >> 6;
    if (lane == 0) wsum[wvi] = s;
    __syncthreads();
    if (threadIdx.x == 0)
        pooled[bc] = (wsum[0] + wsum[1] + wsum[2] + wsum[3]) * (1.0f / (HH * WW));
}

__global__ __launch_bounds__(256) void att_kernel(const float* __restrict__ pooled,
                                                  const float* __restrict__ fc1_w,
                                                  const float* __restrict__ fc2_w,
                                                  const float* __restrict__ fc2_b,
                                                  const float* __restrict__ bias_k,
                                                  float* __restrict__ att,
                                                  float* __restrict__ agg_b) {
    __shared__ float h_lds[BATCH][HID];
    __shared__ float logit_lds[BATCH][KNUM];
    __shared__ float att_lds[BATCH][KNUM];
    for (int idx = threadIdx.x; idx < BATCH * HID; idx += 256) {
        int b = idx / HID, j = idx - b * HID;
        float s = 0.f;
        for (int c = 0; c < CIN; ++c) s += pooled[b * CIN + c] * fc1_w[j * CIN + c];
        h_lds[b][j] = (s >= 0.f) ? s : 0.2f * s;
    }
    __syncthreads();
    if (threadIdx.x < BATCH * KNUM) {
        int b = threadIdx.x / KNUM, k = threadIdx.x - b * KNUM;
        float s = fc2_b[k];
        for (int j = 0; j < HID; ++j) s += h_lds[b][j] * fc2_w[k * HID + j];
        logit_lds[b][k] = s * (1.0f / 34.0f);
    }
    __syncthreads();
    if (threadIdx.x < BATCH) {
        int b = threadIdx.x;
        float m = logit_lds[b][0];
        for (int k = 1; k < KNUM; ++k) m = fmaxf(m, logit_lds[b][k]);
        float e[KNUM], sum = 0.f;
        for (int k = 0; k < KNUM; ++k) { e[k] = expf(logit_lds[b][k] - m); sum += e[k]; }
        float inv = 1.0f / sum;
        for (int k = 0; k < KNUM; ++k) { att_lds[b][k] = e[k] * inv; att[b * KNUM + k] = e[k] * inv; }
    }
    __syncthreads();
    for (int idx = threadIdx.x; idx < BATCH * COUT; idx += 256) {
        int b = idx / COUT, o = idx - b * COUT;
        float s = 0.f;
        for (int k = 0; k < KNUM; ++k) s += att_lds[b][k] * bias_k[k * COUT + o];
        agg_b[idx] = s;
    }
}

__global__ __launch_bounds__(256) void aggw_kernel(const float* __restrict__ att,
                                                   const float* __restrict__ weight,
                                                   unsigned* __restrict__ agg_wb) {
    const int total = BATCH * 9 * COUT * (CIN / 2);
    const size_t kstride = (size_t)COUT * CIN * 9;
    for (int d = blockIdx.x * 256 + threadIdx.x; d < total; d += gridDim.x * 256) {
        int b = d / (9 * COUT * 32);
        int rem = d - b * (9 * COUT * 32);
        int t = rem / (COUT * 32);
        int rem2 = rem - t * (COUT * 32);
        int o = rem2 >> 5, ip = rem2 & 31, i = ip * 2;
        float a0 = att[b * KNUM + 0], a1 = att[b * KNUM + 1];
        float a2 = att[b * KNUM + 2], a3 = att[b * KNUM + 3];
        const float* w0 = weight + ((size_t)(o * CIN + i) * 9 + t);
        float s0 = a0 * w0[0] + a1 * w0[kstride] + a2 * w0[2 * kstride] + a3 * w0[3 * kstride];
        const float* w1 = w0 + 9;
        float s1 = a0 * w1[0] + a1 * w1[kstride] + a2 * w1[2 * kstride] + a3 * w1[3 * kstride];
        agg_wb[d] = (unsigned)f2bf(s0) | ((unsigned)f2bf(s1) << 16);
    }
}

__global__ __launch_bounds__(256) void conv_kernel(
    const float* __restrict__ x, const unsigned* __restrict__ agg_wb,
    const float* __restrict__ agg_b, float* __restrict__ out)
{
    __shared__ short xs[NPIX * XSTR];
    unsigned* xs32 = (unsigned*)xs;
    const int tid = threadIdx.x;
    const int lane = tid & 63;
    const int wv = tid >> 6;
    const int l15 = lane & 15;
    const int q = lane >> 4;
    const int b = blockIdx.z;
    const int r0 = blockIdx.y * TH;
    const int c0 = blockIdx.x * TW;
    {
        const float* xb = x + (size_t)b * CIN * HH * WW;
        #pragma unroll 4
        for (int ig = 0; ig < CIN / 4; ++ig) {
            const float* p0 = xb + (size_t)(4 * ig) * (HH * WW);
            for (int pix = tid; pix < NPIX; pix += 256) {
                int rr = pix / XCOLS, cc = pix - rr * XCOLS;
                int gr = r0 - 1 + rr, gc = c0 - 1 + cc;
                float v0 = 0.f, v1 = 0.f, v2 = 0.f, v3 = 0.f;
                if ((unsigned)gr < HH && (unsigned)gc < WW) {
                    int off = gr * WW + gc;
                    v0 = p0[off]; v1 = p0[off + HH * WW];
                    v2 = p0[off + 2 * HH * WW]; v3 = p0[off + 3 * HH * WW];
                }
                uint2 pk;
                pk.x = (unsigned)f2bf(v0) | ((unsigned)f2bf(v1) << 16);
                pk.y = (unsigned)f2bf(v2) | ((unsigned)f2bf(v3) << 16);
                *(uint2*)(xs32 + pix * XSTR32 + ig * 2) = pk;
            }
        }
    }
    __syncthreads();
    const unsigned* wb = agg_wb + (size_t)b * (9 * COUT * (CIN / 2));
    f32x4 acc[4][4];
    #pragma unroll
    for (int mt = 0; mt < 4; ++mt)
        #pragma unroll
        for (int nt = 0; nt < 4; ++nt) acc[mt][nt] = (f32x4){0.f, 0.f, 0.f, 0.f};
    for (int t = 0; t < 9; ++t) {
        const int dh = t / 3, dw = t - dh * 3;
        #pragma unroll
        for (int ic = 0; ic < 2; ++ic) {
            s16x8 af[4];
            #pragma unroll
            for (int mt = 0; mt < 4; ++mt)
                af[mt] = *(const s16x8*)(wb + ((t * COUT + mt * 16 + l15) * 32 + ic * 16 + q * 4));
            s16x8 bfr[4];
            #pragma unroll
            for (int nt = 0; nt < 4; ++nt) {
                int rr = nt >> 1, cc = nt & 1;
                int pix = (2 * wv + rr + dh) * XCOLS + cc * 16 + l15 + dw;
                bfr[nt] = *(const s16x8*)(xs + pix * XSTR + ic * 32 + q * 8);
            }
            #pragma unroll
            for (int mt = 0; mt < 4; ++mt)
                #pragma unroll
                for (int nt = 0; nt < 4; ++nt)
                    acc[mt][nt] = __builtin_amdgcn_mfma_f32_16x16x32_bf16(af[mt], bfr[nt], acc[mt][nt], 0, 0, 0);
        }
    }
    const float* bbp = agg_b + b * COUT;
    float* op = out + (size_t)b * COUT * HH * WW;
    #pragma unroll
    for (int mt = 0; mt < 4; ++mt)
        #pragma unroll
        for (int rg = 0; rg < 4; ++rg) {
            int o = mt * 16 + q * 4 + rg;
            float bv = bbp[o];
            #pragma unroll
            for (int nt = 0; nt < 4; ++nt) {
                int rr = nt >> 1, cc = nt & 1;
                op[((size_t)o * HH + (r0 + 2 * wv + rr)) * WW + c0 + cc * 16 + l15] = acc[mt][nt][rg] + bv;
            }
        }
}

// ================= launcher =================
extern "C" void kernel_launch(void* const* d_in, const int* in_sizes, int n_in,
                              void* d_out, int out_size, void* d_ws, size_t ws_size,
                              hipStream_t stream) {
    const float* x      = (const float*)d_in[0];
    const float* fc1_w  = (const float*)d_in[1];
    const float* fc2_w  = (const float*)d_in[2];
    const float* fc2_b  = (const float*)d_in[3];
    const float* weight = (const float*)d_in[4];
    const float* bias_k = (const float*)d_in[5];
    float* out = (float*)d_out;
    float* ws  = (float*)d_ws;

    // new-path layout
    float*    pooled = ws;                        // 1024 f32 (sums)
    float*    agg_b  = ws + 1024;                 // 1024 f32
    unsigned* agg_wb = (unsigned*)(ws + 2048);    // 294912 u32
    short*    xpad   = (short*)(ws + 296960);     // 135,266,304 B
    const size_t REQ = (size_t)296960 * 4 + (size_t)BATCH * 256 * 258 * 64 * 2;  // 136,454,144

    if (ws_size >= REQ) {
        hipMemsetAsync(pooled, 0, BATCH * CIN * sizeof(float), stream);
        tpose_pool_kernel<<<dim3(2, 256, BATCH), dim3(256), 0, stream>>>(x, xpad, pooled);
        att_aggw_kernel<<<dim3(9, BATCH), dim3(256), 0, stream>>>(pooled, fc1_w, fc2_w, fc2_b,
                                                                  bias_k, weight, agg_b, agg_wb);
        conv_nhwc_kernel<<<dim3(4096), dim3(256), 0, stream>>>(xpad, agg_wb, agg_b, out);
    } else {
        float* pooled2 = ws;
        float* att2    = ws + 1024;
        float* agg_b2  = ws + 1088;
        unsigned* agg_wb2 = (unsigned*)(ws + 2112);
        pool_kernel<<<dim3(BATCH * CIN), dim3(256), 0, stream>>>(x, pooled2);
        att_kernel<<<dim3(1), dim3(256), 0, stream>>>(pooled2, fc1_w, fc2_w, fc2_b, bias_k, att2, agg_b2);
        aggw_kernel<<<dim3(1152), dim3(256), 0, stream>>>(att2, weight, agg_wb2);
        conv_kernel<<<dim3(WW / TW, HH / TH, BATCH), dim3(256), 0, stream>>>(x, agg_wb2, agg_b2, out);
    }
}